// Round 3
// baseline (238.418 us; speedup 1.0000x reference)
//
#include <hip/hip_runtime.h>
#include <hip/hip_bf16.h>
#include <math.h>

#define T_DIM 1024
#define B_DIM 32
#define DIMF 512
#define DIMH 512
#define DIMS 1024
#define DIMW 512

typedef __attribute__((ext_vector_type(8))) short short8;
typedef __attribute__((ext_vector_type(4))) float f32x4;

__device__ __forceinline__ unsigned f2bf1(float x) {
    unsigned a = __float_as_uint(x);
    return (a + 0x7FFFu + ((a >> 16) & 1u)) >> 16;
}
__device__ __forceinline__ unsigned f2bf2(float lo, float hi) {
    return f2bf1(lo) | (f2bf1(hi) << 16);
}

// async global->LDS, 16B per lane; lptr must be wave-uniform
__device__ __forceinline__ void gl16(const unsigned short* g, unsigned short* l) {
    __builtin_amdgcn_global_load_lds(
        (const __attribute__((address_space(1))) unsigned int*)g,
        (__attribute__((address_space(3))) unsigned int*)l, 16, 0, 0);
}

// ---------------- GT[w][k] = bf16( (F @ Uw)^T ) ----------------
__global__ void k_G_gt(const float* __restrict__ F, const float* __restrict__ Uw,
                       unsigned short* __restrict__ GT) {
    __shared__ float Fs[16][DIMF];
    const int r0 = blockIdx.x * 16;
    const int c  = blockIdx.y * 256 + threadIdx.x;
    const float4* Fv  = (const float4*)(F + (size_t)r0 * DIMF);
    float4* Fsv = (float4*)&Fs[0][0];
    for (int i = threadIdx.x; i < 16 * DIMF / 4; i += 256) Fsv[i] = Fv[i];
    __syncthreads();
    float acc[16];
#pragma unroll
    for (int r = 0; r < 16; ++r) acc[r] = 0.f;
    for (int k = 0; k < DIMF; ++k) {
        const float bv = Uw[(size_t)k * DIMW + c];
#pragma unroll
        for (int r = 0; r < 16; ++r) acc[r] = fmaf(Fs[r][k], bv, acc[r]);
    }
    uint4 o0, o1;
    o0.x = f2bf2(acc[0], acc[1]);   o0.y = f2bf2(acc[2], acc[3]);
    o0.z = f2bf2(acc[4], acc[5]);   o0.w = f2bf2(acc[6], acc[7]);
    o1.x = f2bf2(acc[8], acc[9]);   o1.y = f2bf2(acc[10], acc[11]);
    o1.z = f2bf2(acc[12], acc[13]); o1.w = f2bf2(acc[14], acc[15]);
    *(uint4*)(GT + (size_t)c * T_DIM + r0)     = o0;
    *(uint4*)(GT + (size_t)c * T_DIM + r0 + 8) = o1;
}

// ---------------- SW[b,:] = s_prev[b,:] @ Ww + Vb (fp32) ----------------
__global__ void k_SW(const float* __restrict__ s_prev, const float* __restrict__ Ww,
                     const float* __restrict__ Vb, float* __restrict__ SW) {
    __shared__ float ss[DIMS];
    const int b = blockIdx.x;
    for (int i = threadIdx.x; i < DIMS / 4; i += 256)
        ((float4*)ss)[i] = ((const float4*)(s_prev + (size_t)b * DIMS))[i];
    __syncthreads();
    const int c0 = threadIdx.x, c1 = threadIdx.x + 256;
    float a0 = Vb[c0], a1 = Vb[c1];
    for (int k = 0; k < DIMS; ++k) {
        const float sv = ss[k];
        a0 = fmaf(sv, Ww[(size_t)k * DIMW + c0], a0);
        a1 = fmaf(sv, Ww[(size_t)k * DIMW + c1], a1);
    }
    SW[(size_t)b * DIMW + c0] = a0;
    SW[(size_t)b * DIMW + c1] = a1;
}

// ---------------- VwT[n][k] = bf16(Vw[k][n]) ----------------
__global__ void k_pack_vwT(const float* __restrict__ Vw, unsigned short* __restrict__ VwT) {
    __shared__ float t[32][33];
    const int k0 = blockIdx.x * 32, n0 = blockIdx.y * 32;
    const int x = threadIdx.x & 31, y = threadIdx.x >> 5;
#pragma unroll
    for (int i = 0; i < 4; ++i)
        t[y + 8 * i][x] = Vw[(size_t)(k0 + y + 8 * i) * DIMW + n0 + x];
    __syncthreads();
#pragma unroll
    for (int i = 0; i < 4; ++i)
        VwT[(size_t)(n0 + y + 8 * i) * DIMH + k0 + x] = (unsigned short)f2bf1(t[x][y + 8 * i]);
}

// ---------------- P[b][s][i] = bf16(a_logical[b][i+s]), 8 staggered copies ----------------
__global__ void k_pack_a(const float* __restrict__ a_prev, unsigned short* __restrict__ P) {
    const int bs = blockIdx.x;
    const int b = bs >> 3, s = bs & 7;
    for (int i = threadIdx.x; i < 2048; i += 256) {
        const int j = i + s;
        float v = 0.f;
        if (j >= 512 && j < 1536) v = a_prev[(size_t)b * T_DIM + j - 512];
        P[(size_t)bs * 2048 + i] = (unsigned short)f2bf1(v);
    }
}

// ---------------- hB[(b,t)][k] = bf16(h[t][b][k]) ----------------
__global__ void k_pack_h(const float* __restrict__ h, unsigned short* __restrict__ hB) {
    for (int i = blockIdx.x * 256 + threadIdx.x; i < 32768 * 128; i += gridDim.x * 256) {
        const int r = i >> 7, k4 = (i & 127) * 4;
        const int b = r >> 10, t = r & 1023;
        const float4 v = *(const float4*)(h + ((size_t)(t * 32 + b)) * 512 + k4);
        ushort4 o;
        o.x = (unsigned short)f2bf1(v.x); o.y = (unsigned short)f2bf1(v.y);
        o.z = (unsigned short)f2bf1(v.z); o.w = (unsigned short)f2bf1(v.w);
        *(ushort4*)(hB + (size_t)r * 512 + k4) = o;
    }
}

__global__ void k_zero(float* __restrict__ p, int n) {
    int i = blockIdx.x * 256 + threadIdx.x;
    if (i < n) p[i] = 0.f;
}

// ---------------- main fused MFMA kernel (m97 structure) ----------------
// 1D grid 1024 blocks, 256 threads (4 waves, 2x2), tile 128(M)x128(N)
template <bool PACKED>
__global__ void __launch_bounds__(256) k_main(
    const float* __restrict__ hF, const unsigned short* __restrict__ hB,
    const unsigned short* __restrict__ VwT, const unsigned short* __restrict__ GT,
    const unsigned short* __restrict__ P, const float* __restrict__ SW,
    const float* __restrict__ ww, float* __restrict__ e) {
    __shared__ unsigned short As[128 * 32];
    __shared__ unsigned short Bs[128 * 32];

    // XCD swizzle: 4 n-tiles of one row-panel stay on one XCD (1024 % 8 == 0, bijective)
    const int bid = blockIdx.x;
    const int wg  = (bid & 7) * 128 + (bid >> 3);
    const int x = wg & 3, y = wg >> 2;
    const int w0 = x * 128;
    const int b  = y >> 3;
    const int t0 = (y & 7) * 128;

    const int tid  = threadIdx.x;
    const int lane = tid & 63;
    const int wv   = tid >> 6;
    const int wm = wv >> 1, wn = wv & 1;
    const int g = lane >> 4, r16 = lane & 15;
    const int rowc = lane >> 2, kq = lane & 3;   // staging: 16 rows x 4 k-quarters

    f32x4 acc[4][4];
#pragma unroll
    for (int m = 0; m < 4; ++m)
#pragma unroll
        for (int n = 0; n < 4; ++n) acc[m][n] = (f32x4)0.f;

    // fragment read pointers (elems); row stride 32
    const unsigned short* ApR = &As[(wm * 64 + r16) * 32 + g * 8];
    const unsigned short* BpR = &Bs[(wn * 64 + r16) * 32 + g * 8];
    unsigned short* AsW0 = &As[(wv * 32) * 32];        // wave-uniform LDS dests
    unsigned short* AsW1 = &As[(wv * 32 + 16) * 32];
    unsigned short* BsW0 = &Bs[(wv * 32) * 32];
    unsigned short* BsW1 = &Bs[(wv * 32 + 16) * 32];

    // ================= part 1: h^T @ Vw (K = 512) =================
    for (int k0 = 0; k0 < DIMH; k0 += 32) {
        if (PACKED) {
            __syncthreads();   // previous reads done
            const unsigned short* ga =
                hB + ((size_t)(b * 1024 + t0 + wv * 32 + rowc)) * 512 + k0 + kq * 8;
            gl16(ga, AsW0);
            gl16(ga + 16 * 512, AsW1);
            const unsigned short* gb =
                VwT + ((size_t)(w0 + wv * 32 + rowc)) * 512 + k0 + kq * 8;
            gl16(gb, BsW0);
            gl16(gb + 16 * 512, BsW1);
            __syncthreads();   // vmcnt drained by barrier
        } else {
            const int tA = tid >> 1, cA = (tid & 1) * 16;
            const float* ha = hF + ((size_t)(t0 + tA) * 32 + b) * 512 + k0 + cA;
            const float4 f0 = *(const float4*)(ha);
            const float4 f1 = *(const float4*)(ha + 4);
            const float4 f2 = *(const float4*)(ha + 8);
            const float4 f3 = *(const float4*)(ha + 12);
            uint4 o0, o1;
            o0.x = f2bf2(f0.x, f0.y); o0.y = f2bf2(f0.z, f0.w);
            o0.z = f2bf2(f1.x, f1.y); o0.w = f2bf2(f1.z, f1.w);
            o1.x = f2bf2(f2.x, f2.y); o1.y = f2bf2(f2.z, f2.w);
            o1.z = f2bf2(f3.x, f3.y); o1.w = f2bf2(f3.z, f3.w);
            __syncthreads();
            const unsigned short* gb =
                VwT + ((size_t)(w0 + wv * 32 + rowc)) * 512 + k0 + kq * 8;
            gl16(gb, BsW0);
            gl16(gb + 16 * 512, BsW1);
            *(uint4*)&As[tA * 32 + cA] = o0;
            *(uint4*)&As[tA * 32 + cA + 8] = o1;
            __syncthreads();
        }
        short8 af[4], bfv[4];
#pragma unroll
        for (int m = 0; m < 4; ++m) af[m]  = *(const short8*)(ApR + m * 16 * 32);
#pragma unroll
        for (int n = 0; n < 4; ++n) bfv[n] = *(const short8*)(BpR + n * 16 * 32);
#pragma unroll
        for (int m = 0; m < 4; ++m)
#pragma unroll
            for (int n = 0; n < 4; ++n)
                acc[m][n] = __builtin_amdgcn_mfma_f32_16x16x32_bf16(af[m], bfv[n], acc[m][n], 0, 0, 0);
    }

    // ================= part 2: Toeplitz(a) @ G =================
    const int kstart = max(0, t0 - 512);
    const int kend_  = min(T_DIM - 1, t0 + 128 - 1 + 511);
    const unsigned short* Pb = P + (size_t)b * 8 * 2048;

    short8 afc[4];
#pragma unroll
    for (int m = 0; m < 4; ++m) {
        const int trow = t0 + wm * 64 + m * 16 + r16;
        const int j0 = kstart + g * 8 + 1024 - trow;
        const int s = j0 & 7;
        short8 raw = *(const short8*)(Pb + s * 2048 + (j0 - s));
        afc[m] = (trow == 0) ? (short8)(short)0 : raw;
    }

    for (int k0 = kstart; k0 <= kend_; k0 += 32) {
        __syncthreads();   // previous Bs reads done
        const unsigned short* gb =
            GT + ((size_t)(w0 + wv * 32 + rowc)) * T_DIM + k0 + kq * 8;
        gl16(gb, BsW0);
        gl16(gb + 16 * T_DIM, BsW1);
        __syncthreads();

        short8 afn[4];
#pragma unroll
        for (int m = 0; m < 4; ++m) afn[m] = (short8)(short)0;
        if (k0 + 32 <= kend_) {
#pragma unroll
            for (int m = 0; m < 4; ++m) {
                const int trow = t0 + wm * 64 + m * 16 + r16;
                const int j0 = k0 + 32 + g * 8 + 1024 - trow;
                const int s = j0 & 7;
                short8 raw = *(const short8*)(Pb + s * 2048 + (j0 - s));
                afn[m] = (trow == 0) ? (short8)(short)0 : raw;
            }
        }
        short8 bfv[4];
#pragma unroll
        for (int n = 0; n < 4; ++n) bfv[n] = *(const short8*)(BpR + n * 16 * 32);
#pragma unroll
        for (int m = 0; m < 4; ++m)
#pragma unroll
            for (int n = 0; n < 4; ++n)
                acc[m][n] = __builtin_amdgcn_mfma_f32_16x16x32_bf16(afc[m], bfv[n], acc[m][n], 0, 0, 0);
#pragma unroll
        for (int m = 0; m < 4; ++m) afc[m] = afn[m];
    }

    // ================= epilogue: tanh, dot ww, reduce, atomicAdd =================
    float swv[4], wwv[4];
#pragma unroll
    for (int n = 0; n < 4; ++n) {
        const int w = w0 + wn * 64 + n * 16 + r16;
        swv[n] = SW[(size_t)b * DIMW + w];
        wwv[n] = ww[w];
    }
#pragma unroll
    for (int m = 0; m < 4; ++m) {
#pragma unroll
        for (int reg = 0; reg < 4; ++reg) {
            float s = 0.f;
#pragma unroll
            for (int n = 0; n < 4; ++n)
                s = fmaf(tanhf(acc[m][n][reg] + swv[n]), wwv[n], s);
            s += __shfl_xor(s, 1, 64);
            s += __shfl_xor(s, 2, 64);
            s += __shfl_xor(s, 4, 64);
            s += __shfl_xor(s, 8, 64);
            if (r16 == 0) {
                const int trow = t0 + wm * 64 + m * 16 + g * 4 + reg;
                atomicAdd(&e[(size_t)b * T_DIM + trow], s);
            }
        }
    }
}

// ---------------- softmax over t per batch ----------------
__device__ __forceinline__ float decode_beta(const void* p) {
    const int iv = *(const int*)p;
    const float fv = __int_as_float(iv);
    const float afv = fabsf(fv);
    if (afv >= 1e-6f && afv <= 1e6f) return fv;
    return (float)iv;
}

__global__ void k_softmax(const float* __restrict__ e, const void* __restrict__ beta_p,
                          float* __restrict__ out) {
    const int b = blockIdx.x;
    const float beta = decode_beta(beta_p);
    __shared__ float redm[4];
    __shared__ float reds[4];
    float v[4];
    float m = -INFINITY;
#pragma unroll
    for (int i = 0; i < 4; ++i) {
        v[i] = beta * e[(size_t)b * T_DIM + threadIdx.x * 4 + i];
        m = fmaxf(m, v[i]);
    }
    for (int off = 1; off < 64; off <<= 1) m = fmaxf(m, __shfl_xor(m, off, 64));
    const int wid = threadIdx.x >> 6, lane = threadIdx.x & 63;
    if (lane == 0) redm[wid] = m;
    __syncthreads();
    m = fmaxf(fmaxf(redm[0], redm[1]), fmaxf(redm[2], redm[3]));
    float s = 0.f;
    float ex[4];
#pragma unroll
    for (int i = 0; i < 4; ++i) { ex[i] = expf(v[i] - m); s += ex[i]; }
    for (int off = 1; off < 64; off <<= 1) s += __shfl_xor(s, off, 64);
    if (lane == 0) reds[wid] = s;
    __syncthreads();
    s = reds[0] + reds[1] + reds[2] + reds[3];
    const float inv = 1.f / s;
#pragma unroll
    for (int i = 0; i < 4; ++i)
        out[(size_t)b * T_DIM + threadIdx.x * 4 + i] = ex[i] * inv;
}

extern "C" void kernel_launch(void* const* d_in, const int* in_sizes, int n_in,
                              void* d_out, int out_size, void* d_ws, size_t ws_size,
                              hipStream_t stream) {
    const float* F      = (const float*)d_in[0];
    const float* a_prev = (const float*)d_in[1];
    const float* s_prev = (const float*)d_in[2];
    const float* h      = (const float*)d_in[3];
    const float* Ww     = (const float*)d_in[4];
    const float* Vw     = (const float*)d_in[5];
    const float* Vb     = (const float*)d_in[6];
    const float* Uw     = (const float*)d_in[7];
    const float* ww     = (const float*)d_in[8];
    const void*  beta_p = d_in[9];
    float* out = (float*)d_out;

    char* ws = (char*)d_ws;
    unsigned short* GT  = (unsigned short*)(ws);                        // 1 MB
    unsigned short* VwT = (unsigned short*)(ws + (1u << 20));           // 512 KB
    unsigned short* P   = (unsigned short*)(ws + (1u << 20) + (512u << 10));  // 1 MB
    float* SW = (float*)(ws + (2u << 20) + (512u << 10));               // 64 KB
    float* e  = (float*)(ws + (2u << 20) + (512u << 10) + (64u << 10)); // 128 KB
    unsigned short* hB = (unsigned short*)(ws + (4u << 20));            // 32 MB (if available)

    const bool big = ws_size >= (36ull << 20);

    k_G_gt    <<<dim3(64, 2),  256, 0, stream>>>(F, Uw, GT);
    k_SW      <<<dim3(32),     256, 0, stream>>>(s_prev, Ww, Vb, SW);
    k_pack_vwT<<<dim3(16, 16), 256, 0, stream>>>(Vw, VwT);
    k_pack_a  <<<dim3(256),    256, 0, stream>>>(a_prev, P);
    k_zero    <<<dim3(128),    256, 0, stream>>>(e, B_DIM * T_DIM);
    if (big) {
        k_pack_h<<<dim3(2048), 256, 0, stream>>>(h, hB);
        k_main<true><<<dim3(1024), 256, 0, stream>>>(h, hB, VwT, GT, P, SW, ww, e);
    } else {
        k_main<false><<<dim3(1024), 256, 0, stream>>>(h, hB, VwT, GT, P, SW, ww, e);
    }
    k_softmax <<<dim3(32),     256, 0, stream>>>(e, beta_p, out);
}

// Round 5
// 182.345 us; speedup vs baseline: 1.3075x; 1.3075x over previous
//
#include <hip/hip_runtime.h>
#include <hip/hip_bf16.h>
#include <math.h>

#define T_DIM 1024
#define B_DIM 32
#define DIMF 512
#define DIMH 512
#define DIMS 1024
#define DIMW 512

typedef __attribute__((ext_vector_type(8))) short short8;
typedef __attribute__((ext_vector_type(4))) float f32x4;

__device__ __forceinline__ unsigned f2bf1(float x) {
    unsigned a = __float_as_uint(x);
    return (a + 0x7FFFu + ((a >> 16) & 1u)) >> 16;
}
__device__ __forceinline__ unsigned f2bf2(float lo, float hi) {
    return f2bf1(lo) | (f2bf1(hi) << 16);
}
__device__ __forceinline__ float fast_tanh(float x) {
    return 1.f - __fdividef(2.f, 1.f + __expf(x + x));
}

// async global->LDS, 16B per lane; LDS dest must be wave-uniform (lane*16B implicit)
__device__ __forceinline__ void gl16(const unsigned short* g, unsigned short* l) {
    __builtin_amdgcn_global_load_lds(
        (const __attribute__((address_space(1))) unsigned int*)g,
        (__attribute__((address_space(3))) unsigned int*)l, 16, 0, 0);
}

// ---- GT[w][kblk | chunk-swizzled] = bf16((F@Uw)^T), chunk L at L^((w&3)<<3) ----
__global__ void k_G_gt(const float* __restrict__ F, const float* __restrict__ Uw,
                       unsigned short* __restrict__ GT) {
    __shared__ float Fs[16][DIMF];
    const int r0 = blockIdx.x * 16;
    const int c  = blockIdx.y * 256 + threadIdx.x;
    const float4* Fv  = (const float4*)(F + (size_t)r0 * DIMF);
    float4* Fsv = (float4*)&Fs[0][0];
    for (int i = threadIdx.x; i < 16 * DIMF / 4; i += 256) Fsv[i] = Fv[i];
    __syncthreads();
    float acc[16];
#pragma unroll
    for (int r = 0; r < 16; ++r) acc[r] = 0.f;
    for (int k = 0; k < DIMF; ++k) {
        const float bv = Uw[(size_t)k * DIMW + c];
#pragma unroll
        for (int r = 0; r < 16; ++r) acc[r] = fmaf(Fs[r][k], bv, acc[r]);
    }
    uint4 o0, o1;
    o0.x = f2bf2(acc[0], acc[1]);   o0.y = f2bf2(acc[2], acc[3]);
    o0.z = f2bf2(acc[4], acc[5]);   o0.w = f2bf2(acc[6], acc[7]);
    o1.x = f2bf2(acc[8], acc[9]);   o1.y = f2bf2(acc[10], acc[11]);
    o1.z = f2bf2(acc[12], acc[13]); o1.w = f2bf2(acc[14], acc[15]);
    const int s3 = (c & 3) << 3;
    unsigned short* gout = GT + (size_t)c * T_DIM + (r0 & ~31);
    const int off0 = (r0 & 31) ^ s3;
    *(uint4*)(gout + off0)       = o0;
    *(uint4*)(gout + (off0 ^ 8)) = o1;
}

// ---- SWp[q][b][c] partial of s_prev@Ww (+Vb at q==0), grid (32,4) ----
__global__ void k_SW(const float* __restrict__ s_prev, const float* __restrict__ Ww,
                     const float* __restrict__ Vb, float* __restrict__ SWp) {
    __shared__ float ss[256];
    const int b = blockIdx.x, q = blockIdx.y;
    if (threadIdx.x < 64)
        ((float4*)ss)[threadIdx.x] =
            ((const float4*)(s_prev + (size_t)b * DIMS + q * 256))[threadIdx.x];
    __syncthreads();
    const int c0 = threadIdx.x, c1 = threadIdx.x + 256;
    float a0 = (q == 0) ? Vb[c0] : 0.f;
    float a1 = (q == 0) ? Vb[c1] : 0.f;
    const float* W = Ww + (size_t)q * 256 * DIMW;
    for (int k = 0; k < 256; ++k) {
        const float sv = ss[k];
        a0 = fmaf(sv, W[(size_t)k * DIMW + c0], a0);
        a1 = fmaf(sv, W[(size_t)k * DIMW + c1], a1);
    }
    SWp[((size_t)q * B_DIM + b) * DIMW + c0] = a0;
    SWp[((size_t)q * B_DIM + b) * DIMW + c1] = a1;
}

// ---- VwT[n][k ^ ((n&3)<<3)] = bf16(Vw[k][n]) (chunk-swizzled) ----
__global__ void k_pack_vwT(const float* __restrict__ Vw, unsigned short* __restrict__ VwT) {
    __shared__ float t[32][33];
    const int k0 = blockIdx.x * 32, n0 = blockIdx.y * 32;
    const int x = threadIdx.x & 31, y = threadIdx.x >> 5;
#pragma unroll
    for (int i = 0; i < 4; ++i)
        t[y + 8 * i][x] = Vw[(size_t)(k0 + y + 8 * i) * DIMW + n0 + x];
    __syncthreads();
#pragma unroll
    for (int i = 0; i < 4; ++i) {
        const int n = n0 + y + 8 * i;
        const int kk = (k0 + x) ^ ((n & 3) << 3);
        VwT[(size_t)n * DIMH + kk] = (unsigned short)f2bf1(t[x][y + 8 * i]);
    }
}

// ---- P[b][s][i] = bf16(a_logical[b][i+s]), 8 staggered copies ----
__global__ void k_pack_a(const float* __restrict__ a_prev, unsigned short* __restrict__ P) {
    const int bs = blockIdx.x;
    const int b = bs >> 3, s = bs & 7;
    for (int i = threadIdx.x; i < 2048; i += 256) {
        const int j = i + s;
        float v = 0.f;
        if (j >= 512 && j < 1536) v = a_prev[(size_t)b * T_DIM + j - 512];
        P[(size_t)bs * 2048 + i] = (unsigned short)f2bf1(v);
    }
}

// ---------------- main fused MFMA kernel: 2-phase double-buffered ----------------
// grid 1024 (XCD-swizzled), 256 threads (4 waves 2x2), tile 128x128
__global__ void __launch_bounds__(256) k_main(
    const float* __restrict__ hF, const unsigned short* __restrict__ VwT,
    const unsigned short* __restrict__ GT, const unsigned short* __restrict__ P,
    const float* __restrict__ SWp, const float* __restrict__ ww,
    float* __restrict__ ep) {
    __shared__ unsigned short As[2][128 * 32];
    __shared__ unsigned short Bs[2][128 * 32];

    const int bid = blockIdx.x;
    const int wg  = (bid & 7) * 128 + (bid >> 3);   // bijective: 1024 % 8 == 0
    const int x = wg & 3, y = wg >> 2;
    const int w0 = x * 128;
    const int b  = y >> 3;
    const int t0 = (y & 7) * 128;

    const int tid  = threadIdx.x;
    const int lane = tid & 63;
    const int wv   = tid >> 6;
    const int wm = wv >> 1, wn = wv & 1;
    const int g = lane >> 4, r16 = lane & 15;
    const int rowc = lane >> 2, kq = lane & 3;
    const int tA = tid >> 1, cA = (tid & 1) * 16;
    const int sA  = (tA & 3) << 3;
    const int oA0 = cA ^ sA, oA1 = (cA + 8) ^ sA;
    const int gx  = (g * 8) ^ ((r16 & 3) << 3);

    f32x4 acc[4][4];
#pragma unroll
    for (int m = 0; m < 4; ++m)
#pragma unroll
        for (int n = 0; n < 4; ++n) acc[m][n] = (f32x4)0.f;

    const float* hrow = hF + ((size_t)(t0 + tA) * B_DIM + b) * DIMH + cA;
    const unsigned short* vsrc = VwT + (size_t)(w0 + wv * 32 + rowc) * DIMH + kq * 8;
    const unsigned short* gsrc = GT  + (size_t)(w0 + wv * 32 + rowc) * T_DIM + kq * 8;
    const int ArBase = (wm * 64 + r16) * 32 + gx;
    const int BrBase = (wn * 64 + r16) * 32 + gx;

    int cur = 0;

    // ---- prologue: stage step 0 ----
    {
        const float4 f0 = *(const float4*)(hrow);
        const float4 f1 = *(const float4*)(hrow + 4);
        const float4 f2 = *(const float4*)(hrow + 8);
        const float4 f3 = *(const float4*)(hrow + 12);
        unsigned short* bdst = &Bs[0][wv * 1024];
        gl16(vsrc, bdst);
        gl16(vsrc + 16 * DIMH, bdst + 512);
        uint4 o0, o1;
        o0.x = f2bf2(f0.x, f0.y); o0.y = f2bf2(f0.z, f0.w);
        o0.z = f2bf2(f1.x, f1.y); o0.w = f2bf2(f1.z, f1.w);
        o1.x = f2bf2(f2.x, f2.y); o1.y = f2bf2(f2.z, f2.w);
        o1.z = f2bf2(f3.x, f3.y); o1.w = f2bf2(f3.z, f3.w);
        *(uint4*)&As[0][tA * 32 + oA0] = o0;
        *(uint4*)&As[0][tA * 32 + oA1] = o1;
    }
    __syncthreads();

    // ---- section 1: steps 0..14 (part1), staging part1 step s+1 ----
    for (int s = 0; s < 15; ++s) {
        const int k1 = (s + 1) * 32;
        const float4 f0 = *(const float4*)(hrow + k1);
        const float4 f1 = *(const float4*)(hrow + k1 + 4);
        const float4 f2 = *(const float4*)(hrow + k1 + 8);
        const float4 f3 = *(const float4*)(hrow + k1 + 12);
        unsigned short* bdst = &Bs[cur ^ 1][wv * 1024];
        gl16(vsrc + k1, bdst);
        gl16(vsrc + k1 + 16 * DIMH, bdst + 512);

        const unsigned short* Ar = &As[cur][ArBase];
        const unsigned short* Br = &Bs[cur][BrBase];
        short8 af[4], bf[4];
#pragma unroll
        for (int m = 0; m < 4; ++m) af[m] = *(const short8*)(Ar + m * 512);
#pragma unroll
        for (int n = 0; n < 4; ++n) bf[n] = *(const short8*)(Br + n * 512);
#pragma unroll
        for (int m = 0; m < 4; ++m)
#pragma unroll
            for (int n = 0; n < 4; ++n)
                acc[m][n] = __builtin_amdgcn_mfma_f32_16x16x32_bf16(af[m], bf[n], acc[m][n], 0, 0, 0);

        uint4 o0, o1;
        o0.x = f2bf2(f0.x, f0.y); o0.y = f2bf2(f0.z, f0.w);
        o0.z = f2bf2(f1.x, f1.y); o0.w = f2bf2(f1.z, f1.w);
        o1.x = f2bf2(f2.x, f2.y); o1.y = f2bf2(f2.z, f2.w);
        o1.z = f2bf2(f3.x, f3.y); o1.w = f2bf2(f3.z, f3.w);
        *(uint4*)&As[cur ^ 1][tA * 32 + oA0] = o0;
        *(uint4*)&As[cur ^ 1][tA * 32 + oA1] = o1;
        __syncthreads();
        cur ^= 1;
    }

    // ---- section 2: step 15 (part1 compute), stage first part2 step ----
    const int kstart = max(0, t0 - 512);
    const int kend   = min(T_DIM - 1, t0 + 639);
    const int NS2    = (kend - kstart + 1) >> 5;
    const unsigned short* Pb = P + (size_t)b * 8 * 2048;

    short8 afc[4];
    {
#pragma unroll
        for (int m = 0; m < 4; ++m) {
            const int trow = t0 + wm * 64 + m * 16 + r16;
            const int j0 = kstart + g * 8 + 1024 - trow;
            const int sj = j0 & 7;
            short8 raw = *(const short8*)(Pb + sj * 2048 + (j0 - sj));
            afc[m] = (trow == 0) ? (short8)(short)0 : raw;
        }
        unsigned short* bdst = &Bs[cur ^ 1][wv * 1024];
        gl16(gsrc + kstart, bdst);
        gl16(gsrc + kstart + 16 * T_DIM, bdst + 512);

        const unsigned short* Ar = &As[cur][ArBase];
        const unsigned short* Br = &Bs[cur][BrBase];
        short8 af[4], bf[4];
#pragma unroll
        for (int m = 0; m < 4; ++m) af[m] = *(const short8*)(Ar + m * 512);
#pragma unroll
        for (int n = 0; n < 4; ++n) bf[n] = *(const short8*)(Br + n * 512);
#pragma unroll
        for (int m = 0; m < 4; ++m)
#pragma unroll
            for (int n = 0; n < 4; ++n)
                acc[m][n] = __builtin_amdgcn_mfma_f32_16x16x32_bf16(af[m], bf[n], acc[m][n], 0, 0, 0);
        __syncthreads();
        cur ^= 1;
    }

    // ---- section 3: part2 steps ----
    for (int s2 = 0; s2 < NS2; ++s2) {
        const bool more = (s2 + 1 < NS2);
        short8 afn[4];
        if (more) {
            const int k2 = kstart + (s2 + 1) * 32;
#pragma unroll
            for (int m = 0; m < 4; ++m) {
                const int trow = t0 + wm * 64 + m * 16 + r16;
                const int j0 = k2 + g * 8 + 1024 - trow;
                const int sj = j0 & 7;
                short8 raw = *(const short8*)(Pb + sj * 2048 + (j0 - sj));
                afn[m] = (trow == 0) ? (short8)(short)0 : raw;
            }
            unsigned short* bdst = &Bs[cur ^ 1][wv * 1024];
            gl16(gsrc + k2, bdst);
            gl16(gsrc + k2 + 16 * T_DIM, bdst + 512);
        }
        const unsigned short* Br = &Bs[cur][BrBase];
        short8 bf[4];
#pragma unroll
        for (int n = 0; n < 4; ++n) bf[n] = *(const short8*)(Br + n * 512);
#pragma unroll
        for (int m = 0; m < 4; ++m)
#pragma unroll
            for (int n = 0; n < 4; ++n)
                acc[m][n] = __builtin_amdgcn_mfma_f32_16x16x32_bf16(afc[m], bf[n], acc[m][n], 0, 0, 0);
        if (more) {
#pragma unroll
            for (int m = 0; m < 4; ++m) afc[m] = afn[m];
            __syncthreads();
        }
        cur ^= 1;
    }

    // ---- epilogue: tanh, dot ww, 16-lane reduce, per-(x,wn) partial store ----
    float swv[4], wwv[4];
#pragma unroll
    for (int n = 0; n < 4; ++n) {
        const int w = w0 + wn * 64 + n * 16 + r16;
        float sv = 0.f;
#pragma unroll
        for (int q = 0; q < 4; ++q)
            sv += SWp[((size_t)q * B_DIM + b) * DIMW + w];
        swv[n] = sv;
        wwv[n] = ww[w];
    }
#pragma unroll
    for (int m = 0; m < 4; ++m) {
#pragma unroll
        for (int reg = 0; reg < 4; ++reg) {
            float s = 0.f;
#pragma unroll
            for (int n = 0; n < 4; ++n)
                s = fmaf(fast_tanh(acc[m][n][reg] + swv[n]), wwv[n], s);
            s += __shfl_xor(s, 1, 64);
            s += __shfl_xor(s, 2, 64);
            s += __shfl_xor(s, 4, 64);
            s += __shfl_xor(s, 8, 64);
            if (r16 == 0) {
                const int trow = t0 + wm * 64 + m * 16 + g * 4 + reg;
                // partial index = (w-tile, wn): both wn-waves cover disjoint w-halves
                ep[((size_t)(x * 2 + wn) * B_DIM + b) * T_DIM + trow] = s;
            }
        }
    }
}

// ---------------- softmax over t per batch (sums 8 e-partials) ----------------
__device__ __forceinline__ float decode_beta(const void* p) {
    const int iv = *(const int*)p;
    const float fv = __int_as_float(iv);
    const float afv = fabsf(fv);
    if (afv >= 1e-6f && afv <= 1e6f) return fv;
    return (float)iv;
}

__global__ void k_softmax(const float* __restrict__ ep, const void* __restrict__ beta_p,
                          float* __restrict__ out) {
    const int b = blockIdx.x;
    const float beta = decode_beta(beta_p);
    __shared__ float redm[4];
    __shared__ float reds[4];
    float v[4];
    float m = -INFINITY;
#pragma unroll
    for (int i = 0; i < 4; ++i) {
        const int t = threadIdx.x * 4 + i;
        float ev = 0.f;
#pragma unroll
        for (int xq = 0; xq < 8; ++xq)
            ev += ep[((size_t)xq * B_DIM + b) * T_DIM + t];
        v[i] = beta * ev;
        m = fmaxf(m, v[i]);
    }
    for (int off = 1; off < 64; off <<= 1) m = fmaxf(m, __shfl_xor(m, off, 64));
    const int wid = threadIdx.x >> 6, lane = threadIdx.x & 63;
    if (lane == 0) redm[wid] = m;
    __syncthreads();
    m = fmaxf(fmaxf(redm[0], redm[1]), fmaxf(redm[2], redm[3]));
    float s = 0.f;
    float ex[4];
#pragma unroll
    for (int i = 0; i < 4; ++i) { ex[i] = expf(v[i] - m); s += ex[i]; }
    for (int off = 1; off < 64; off <<= 1) s += __shfl_xor(s, off, 64);
    if (lane == 0) reds[wid] = s;
    __syncthreads();
    s = reds[0] + reds[1] + reds[2] + reds[3];
    const float inv = 1.f / s;
#pragma unroll
    for (int i = 0; i < 4; ++i)
        out[(size_t)b * T_DIM + threadIdx.x * 4 + i] = ex[i] * inv;
}

extern "C" void kernel_launch(void* const* d_in, const int* in_sizes, int n_in,
                              void* d_out, int out_size, void* d_ws, size_t ws_size,
                              hipStream_t stream) {
    const float* F      = (const float*)d_in[0];
    const float* a_prev = (const float*)d_in[1];
    const float* s_prev = (const float*)d_in[2];
    const float* h      = (const float*)d_in[3];
    const float* Ww     = (const float*)d_in[4];
    const float* Vw     = (const float*)d_in[5];
    const float* Vb     = (const float*)d_in[6];
    const float* Uw     = (const float*)d_in[7];
    const float* ww     = (const float*)d_in[8];
    const void*  beta_p = d_in[9];
    float* out = (float*)d_out;

    char* ws = (char*)d_ws;
    unsigned short* GT  = (unsigned short*)(ws);                        // 1 MB
    unsigned short* VwT = (unsigned short*)(ws + (1u << 20));           // 512 KB
    unsigned short* P   = (unsigned short*)(ws + (1u << 20) + (512u << 10));  // 1 MB
    float* SWp = (float*)(ws + (2u << 20) + (512u << 10));              // 256 KB
    float* ep  = (float*)(ws + (2u << 20) + (768u << 10));              // 1 MB (8 partials)

    k_G_gt    <<<dim3(64, 2),  256, 0, stream>>>(F, Uw, GT);
    k_pack_vwT<<<dim3(16, 16), 256, 0, stream>>>(Vw, VwT);
    k_pack_a  <<<dim3(256),    256, 0, stream>>>(a_prev, P);
    k_SW      <<<dim3(32, 4),  256, 0, stream>>>(s_prev, Ww, Vb, SWp);
    k_main    <<<dim3(1024),   256, 0, stream>>>(h, VwT, GT, P, SWp, ww, ep);
    k_softmax <<<dim3(32),     256, 0, stream>>>(ep, beta_p, out);
}